// Round 11
// baseline (897.118 us; speedup 1.0000x reference)
//
#include <hip/hip_runtime.h>
#include <hip/hip_bf16.h>
#include <cstddef>

// ---------------------------------------------------------------------------
// EncoderModule: 5x causal conv1d (K=7) + ELU, then 2x VQ argmin (1024 codes, D=64)
// B=64, L=48000, strides 2,2,2,3,1; channels 1->16->32->64->64->128
// Output: int32 indices, shape (2, 64, 2000)
//
// conv0: fp32 VALU, phase-split store. conv1/conv2: stride-2 conv rewritten as
// stride-1 K=4 conv over phase-split input -> 6-term split-bf16 MFMA.
// conv3/conv4: 6-term split-bf16 MFMA (unchanged numerics).
// VQ: split-bf16 MFMA scores; gap < 0.04 -> flag; paired exact fp32 rescore.
// conv1/conv2 weight fragments staged in d_out (dead until vq_mfma rewrites it).
// ---------------------------------------------------------------------------

using bf16x8 = __attribute__((ext_vector_type(8))) short;
using f32x4  = __attribute__((ext_vector_type(4))) float;

static __device__ __forceinline__ short f2bf(float f) {
    __hip_bfloat16 h = __float2bfloat16(f);   // RNE
    union { __hip_bfloat16 h; short s; } u; u.h = h;
    return u.s;
}
static __device__ __forceinline__ float bf2f(short s) {
    union { unsigned u; float f; } v;
    v.u = ((unsigned)(unsigned short)s) << 16;
    return v.f;
}
static __device__ __forceinline__ void split3(float v, short& s0, short& s1, short& s2) {
    s0 = f2bf(v);  float r1 = v  - bf2f(s0);
    s1 = f2bf(r1); float r2 = r1 - bf2f(s1);
    s2 = f2bf(r2);
}
template<int CIN>
static __device__ __forceinline__ int swz(int r, int off) {
    if constexpr (CIN == 64) return off ^ ((r & 7) << 4);
    else                     return off ^ (((r >> 1) & 3) << 4);
}

// ---------------- conv_wave: conv0 only (CIN=1), phase-split store ----------
template<int CIN, int S, int CO_T, int TT, bool PSOUT>
__global__ __launch_bounds__(256) void conv_wave_kernel(
    const float* __restrict__ x, const float* __restrict__ w,
    const float* __restrict__ bias, float* __restrict__ y,
    int B, int Lin, int Lout, int Cout)
{
    constexpr int NT   = 64 * TT;
    constexpr int XLEN = (NT - 1) * S + 7;
    __shared__ float xs[CIN][XLEN];

    int tb  = blockIdx.x;
    int cbk = blockIdx.y;
    int b   = blockIdx.z;
    int t0  = tb * NT;
    int tid  = threadIdx.x;
    int lane = tid & 63;
    int wv   = __builtin_amdgcn_readfirstlane(tid >> 6);

    const float* xb = x + (size_t)b * CIN * Lin;
    int g0 = t0 * S - 6;
    for (int i = tid; i < CIN * XLEN; i += 256) {
        int ci = i / XLEN, xo = i % XLEN;
        int gx = g0 + xo;
        xs[ci][xo] = (gx >= 0 && gx < Lin) ? xb[(size_t)ci * Lin + gx] : 0.0f;
    }
    __syncthreads();

    int co0 = cbk * (4 * CO_T) + wv * CO_T;
    const float* wbase = w + (size_t)co0 * CIN * 7;

    float acc[CO_T][TT];
    #pragma unroll
    for (int c = 0; c < CO_T; ++c)
        #pragma unroll
        for (int u = 0; u < TT; ++u) acc[c][u] = 0.0f;

    for (int ci = 0; ci < CIN; ++ci) {
        float xw[TT][7];
        #pragma unroll
        for (int u = 0; u < TT; ++u)
            #pragma unroll
            for (int k = 0; k < 7; ++k)
                xw[u][k] = xs[ci][(lane + 64 * u) * S + k];
        #pragma unroll
        for (int c = 0; c < CO_T; ++c) {
            const float* wp = wbase + (size_t)c * CIN * 7 + ci * 7;  // s_load
            #pragma unroll
            for (int k = 0; k < 7; ++k) {
                float wk = wp[k];
                #pragma unroll
                for (int u = 0; u < TT; ++u)
                    acc[c][u] = fmaf(wk, xw[u][k], acc[c][u]);
            }
        }
    }

    #pragma unroll
    for (int u = 0; u < TT; ++u) {
        int t = t0 + lane + 64 * u;
        if (t < Lout) {
            #pragma unroll
            for (int c = 0; c < CO_T; ++c) {
                float v = acc[c][u] + bias[co0 + c];
                v = v > 0.0f ? v : expm1f(v);
                if constexpr (PSOUT)
                    y[((size_t)b * (2 * Cout) + (co0 + c) + Cout * (t & 1)) * (Lout >> 1) + (t >> 1)] = v;
                else
                    y[((size_t)b * Cout + co0 + c) * Lout + t] = v;
            }
        }
    }
}

// ---------------- weight prep: 3-level bf16 A-fragments (direct, 7 taps) ----
template<int CIN, int COUT, int TAPS>
__global__ void wprep_kernel(const float* __restrict__ w, short* __restrict__ frag)
{
    constexpr int KC = CIN / 32;
    int co = threadIdx.x;
    if (co >= COUT) return;
    int mt = co >> 4, nc = co & 15;
    for (int kc = 0; kc < KC; ++kc)
        for (int k = 0; k < TAPS; ++k)
            #pragma unroll
            for (int lh = 0; lh < 4; ++lh) {
                bf16x8 p0, p1, p2;
                #pragma unroll
                for (int j = 0; j < 8; ++j) {
                    int ci = kc * 32 + lh * 8 + j;
                    float f = w[(size_t)co * CIN * 7 + ci * 7 + k];
                    short a, bb, c; split3(f, a, bb, c);
                    p0[j] = a; p1[j] = bb; p2[j] = c;
                }
                size_t base = ((size_t)(mt * KC + kc) * TAPS + k) * 3;
                int off = (lh * 16 + nc) * 8;
                *(bf16x8*)(frag + (base + 0) * 512 + off) = p0;
                *(bf16x8*)(frag + (base + 1) * 512 + off) = p1;
                *(bf16x8*)(frag + (base + 2) * 512 + off) = p2;
            }
}

// ---------------- weight prep: phase-split packing (stride-2 -> K=4) --------
// packed W[co][cp][m]: cp<CINH -> w[co][cp][2m] (m=0..3); cp>=CINH ->
// m<3 ? w[co][cp-CINH][2m+1] : 0
template<int CINH, int COUT>
__global__ void wprep_ps_kernel(const float* __restrict__ w, short* __restrict__ frag)
{
    constexpr int CIN = 2 * CINH;
    constexpr int KC  = CIN / 32;
    int co = threadIdx.x;
    if (co >= COUT) return;
    int mt = co >> 4, nc = co & 15;
    for (int kc = 0; kc < KC; ++kc)
        for (int m = 0; m < 4; ++m)
            #pragma unroll
            for (int lh = 0; lh < 4; ++lh) {
                bf16x8 p0, p1, p2;
                #pragma unroll
                for (int j = 0; j < 8; ++j) {
                    int cp = kc * 32 + lh * 8 + j;
                    float f;
                    if (cp < CINH)      f = w[(size_t)co * CINH * 7 + cp * 7 + 2 * m];
                    else if (m < 3)     f = w[(size_t)co * CINH * 7 + (cp - CINH) * 7 + 2 * m + 1];
                    else                f = 0.0f;
                    short a, bb, c; split3(f, a, bb, c);
                    p0[j] = a; p1[j] = bb; p2[j] = c;
                }
                size_t base = ((size_t)(mt * KC + kc) * 4 + m) * 3;
                int off = (lh * 16 + nc) * 8;
                *(bf16x8*)(frag + (base + 0) * 512 + off) = p0;
                *(bf16x8*)(frag + (base + 1) * 512 + off) = p1;
                *(bf16x8*)(frag + (base + 2) * 512 + off) = p2;
            }
}

// ---------------- conv via 6-term split-bf16 MFMA ---------------------------
template<int S, int CIN, int COUT, int NTL, int TAPS, int PAD, bool PSOUT>
__global__ __launch_bounds__(256) void conv_mfma_kernel(
    const float* __restrict__ hin, const short* __restrict__ wfrag,
    const float* __restrict__ bias, float* __restrict__ yout,
    int Lin, int Lout)
{
    constexpr int KC   = CIN / 32;
    constexpr int MT   = COUT / 16;
    constexpr int NT   = NTL * 64;
    constexpr int ROWS = (NT - 1) * S + TAPS;
    constexpr int ROWB = CIN * 2;
    __shared__ short hl0[ROWS * CIN];
    __shared__ short hl1[ROWS * CIN];
    __shared__ short hl2[ROWS * CIN];

    int nb = blockIdx.x, b = blockIdx.y;
    int t0 = nb * NT;
    int tid = threadIdx.x, lane = tid & 63, wv = tid >> 6;

    const float* hb = hin + (size_t)b * CIN * Lin;
    for (int e = tid; e < CIN * ROWS; e += 256) {
        int ci = e / ROWS, rr = e % ROWS;
        int t = t0 * S - PAD + rr;
        float v = (t >= 0 && t < Lin) ? hb[(size_t)ci * Lin + t] : 0.0f;
        short a, bb, c; split3(v, a, bb, c);
        int byte = rr * ROWB + swz<CIN>(rr, ci * 2);
        *(short*)((char*)hl0 + byte) = a;
        *(short*)((char*)hl1 + byte) = bb;
        *(short*)((char*)hl2 + byte) = c;
    }
    __syncthreads();

    f32x4 acc[NTL][MT];
    #pragma unroll
    for (int n = 0; n < NTL; ++n)
        #pragma unroll
        for (int m = 0; m < MT; ++m) acc[n][m] = (f32x4){0.f, 0.f, 0.f, 0.f};

    int ncol = lane & 15, nq = lane >> 4;

    for (int k = 0; k < TAPS; ++k) {
        #pragma unroll
        for (int kc = 0; kc < KC; ++kc) {
            int colb = (kc * 32 + nq * 8) * 2;
            bf16x8 B0[NTL], B1[NTL], B2[NTL];
            #pragma unroll
            for (int ntl = 0; ntl < NTL; ++ntl) {
                int r = S * ((wv * NTL + ntl) * 16 + ncol) + k;
                int byte = r * ROWB + swz<CIN>(r, colb);
                B0[ntl] = *(const bf16x8*)((const char*)hl0 + byte);
                B1[ntl] = *(const bf16x8*)((const char*)hl1 + byte);
                B2[ntl] = *(const bf16x8*)((const char*)hl2 + byte);
            }
            #pragma unroll
            for (int m = 0; m < MT; ++m) {
                size_t base = ((size_t)(m * KC + kc) * TAPS + k) * 3;
                bf16x8 a0 = *(const bf16x8*)(wfrag + (base + 0) * 512 + lane * 8);
                bf16x8 a1 = *(const bf16x8*)(wfrag + (base + 1) * 512 + lane * 8);
                bf16x8 a2 = *(const bf16x8*)(wfrag + (base + 2) * 512 + lane * 8);
                #pragma unroll
                for (int ntl = 0; ntl < NTL; ++ntl) {
                    f32x4 a = acc[ntl][m];
                    a = __builtin_amdgcn_mfma_f32_16x16x32_bf16(a0, B0[ntl], a, 0, 0, 0);
                    a = __builtin_amdgcn_mfma_f32_16x16x32_bf16(a1, B0[ntl], a, 0, 0, 0);
                    a = __builtin_amdgcn_mfma_f32_16x16x32_bf16(a2, B0[ntl], a, 0, 0, 0);
                    a = __builtin_amdgcn_mfma_f32_16x16x32_bf16(a0, B1[ntl], a, 0, 0, 0);
                    a = __builtin_amdgcn_mfma_f32_16x16x32_bf16(a1, B1[ntl], a, 0, 0, 0);
                    a = __builtin_amdgcn_mfma_f32_16x16x32_bf16(a0, B2[ntl], a, 0, 0, 0);
                    acc[ntl][m] = a;
                }
            }
        }
    }

    #pragma unroll
    for (int ntl = 0; ntl < NTL; ++ntl) {
        int n = t0 + (wv * NTL + ntl) * 16 + ncol;
        if (n < Lout) {
            #pragma unroll
            for (int m = 0; m < MT; ++m) {
                #pragma unroll
                for (int j = 0; j < 4; ++j) {
                    int co = m * 16 + nq * 4 + j;
                    float v = acc[ntl][m][j] + bias[co];
                    v = v > 0.0f ? v : expm1f(v);
                    if constexpr (PSOUT)
                        yout[((size_t)b * (2 * COUT) + co + COUT * (n & 1)) * (Lout >> 1) + (n >> 1)] = v;
                    else
                        yout[((size_t)b * COUT + co) * Lout + n] = v;
                }
            }
        }
    }
}

// ---------------- VQ prep: cc (fp32) + codebook hi/lo bf16 B-fragments ------
__global__ __launch_bounds__(256) void vq_prep_kernel(
    const float* __restrict__ cbs, float* __restrict__ cc, short* __restrict__ cbf)
{
    int c = blockIdx.x * 256 + threadIdx.x;   // 0..2047
    if (c >= 2048) return;
    int cb = c >> 10, nl = c & 1023;
    const float* row = cbs + (size_t)c * 64;
    float v[64];
    float s = 0.f;
    #pragma unroll
    for (int i = 0; i < 16; ++i) {
        float4 q = ((const float4*)row)[i];
        v[4*i+0] = q.x; v[4*i+1] = q.y; v[4*i+2] = q.z; v[4*i+3] = q.w;
        s += q.x*q.x + q.y*q.y + q.z*q.z + q.w*q.w;
    }
    cc[c] = s;
    int nt = nl >> 4, nc = nl & 15;
    #pragma unroll
    for (int kc = 0; kc < 2; ++kc)
        #pragma unroll
        for (int lh = 0; lh < 4; ++lh) {
            bf16x8 ph, pl;
            #pragma unroll
            for (int j = 0; j < 8; ++j) {
                float f = v[kc*32 + lh*8 + j];
                short h = f2bf(f);
                ph[j] = h;
                pl[j] = f2bf(f - bf2f(h));
            }
            size_t base = ((((size_t)cb*64 + nt)*2 + kc)*2);
            *(bf16x8*)(cbf + ((base + 0)*64 + (lh*16 + nc)) * 8) = ph;
            *(bf16x8*)(cbf + ((base + 1)*64 + (lh*16 + nc)) * 8) = pl;
        }
}

__global__ void zero_cnt_kernel(int* cnt) {
    if (threadIdx.x == 0 && blockIdx.x == 0) { cnt[0] = 0; cnt[1] = 0; }
}

// ---------------- VQ main: split-bf16 MFMA + best/second + flag -------------
#define VQ_MARGIN 0.04f

__global__ __launch_bounds__(256) void vq_mfma_kernel(
    const float* __restrict__ z, const short* __restrict__ cbf,
    const float* __restrict__ ccg, int* __restrict__ out,
    int* __restrict__ cnt, int* __restrict__ list0, int* __restrict__ list1)
{
    __shared__ short zf[2][8*2*64*8];
    __shared__ short cbc[8*2*2*64*8];
    __shared__ float ccl[128];

    const int T = 2000;
    int mblk = blockIdx.x;
    int cb   = blockIdx.y;
    int b    = blockIdx.z;
    int t0   = mblk * 128;
    int tid  = threadIdx.x;
    int lane = tid & 63;
    int wv   = tid >> 6;
    int* list = cb ? list1 : list0;

    const float* zb = z + ((size_t)b*128 + (size_t)cb*64) * T;
    bool tail = (t0 + 128 > T);
    #pragma unroll
    for (int p = 0; p < 8; ++p) {
        int d    = p*8 + (tid >> 5);
        int toff = (tid & 31) * 4;
        float qa[4];
        if (!tail) {
            float4 q = *(const float4*)(zb + (size_t)d*T + t0 + toff);
            qa[0]=q.x; qa[1]=q.y; qa[2]=q.z; qa[3]=q.w;
        } else {
            #pragma unroll
            for (int u = 0; u < 4; ++u) {
                int tt = t0 + toff + u; if (tt > T-1) tt = T-1;
                qa[u] = zb[(size_t)d*T + tt];
            }
        }
        #pragma unroll
        for (int u = 0; u < 4; ++u) {
            int tl = toff + u;
            int mt = tl >> 4;
            int lw = ((d & 31) >> 3) * 16 + (tl & 15);
            int kc = d >> 5;
            int idx = (((mt*2 + kc)*64) + lw)*8 + (d & 7);
            short h = f2bf(qa[u]);
            zf[0][idx] = h;
            zf[1][idx] = f2bf(qa[u] - bf2f(h));
        }
    }
    __syncthreads();

    bf16x8 ah[2][2], al[2][2];
    #pragma unroll
    for (int mtl = 0; mtl < 2; ++mtl)
        #pragma unroll
        for (int kc = 0; kc < 2; ++kc) {
            int idx = ((((wv*2+mtl)*2 + kc)*64) + lane)*8;
            ah[mtl][kc] = *(const bf16x8*)&zf[0][idx];
            al[mtl][kc] = *(const bf16x8*)&zf[1][idx];
        }

    float best[2][4], second[2][4]; int bidx[2][4];
    #pragma unroll
    for (int m = 0; m < 2; ++m)
        #pragma unroll
        for (int j = 0; j < 4; ++j) { best[m][j] = 3.4e38f; second[m][j] = 3.4e38f; bidx[m][j] = 0; }

    const short* cbase = cbf + (size_t)cb * (64*2*2*64*8);
    const float* ccb   = ccg + cb * 1024;

    for (int ch = 0; ch < 8; ++ch) {
        __syncthreads();
        {
            const float4* src = (const float4*)(cbase + (size_t)ch * (8*2*2*64*8));
            float4* dst = (float4*)cbc;
            #pragma unroll
            for (int i = 0; i < 8; ++i) dst[tid + 256*i] = src[tid + 256*i];
            if (tid < 128) ccl[tid] = ccb[ch*128 + tid];
        }
        __syncthreads();

        for (int ntl = 0; ntl < 8; ++ntl) {
            bf16x8 b0h = *(const bf16x8*)&cbc[(((ntl*2 + 0)*2 + 0)*64 + lane)*8];
            bf16x8 b0l = *(const bf16x8*)&cbc[(((ntl*2 + 0)*2 + 1)*64 + lane)*8];
            bf16x8 b1h = *(const bf16x8*)&cbc[(((ntl*2 + 1)*2 + 0)*64 + lane)*8];
            bf16x8 b1l = *(const bf16x8*)&cbc[(((ntl*2 + 1)*2 + 1)*64 + lane)*8];
            float ccv = ccl[ntl*16 + (lane & 15)];
            int  code = ch*128 + ntl*16 + (lane & 15);
            #pragma unroll
            for (int mtl = 0; mtl < 2; ++mtl) {
                f32x4 p = {0.f,0.f,0.f,0.f}, q = {0.f,0.f,0.f,0.f};
                p = __builtin_amdgcn_mfma_f32_16x16x32_bf16(ah[mtl][0], b0h, p, 0, 0, 0);
                q = __builtin_amdgcn_mfma_f32_16x16x32_bf16(ah[mtl][1], b1h, q, 0, 0, 0);
                p = __builtin_amdgcn_mfma_f32_16x16x32_bf16(ah[mtl][0], b0l, p, 0, 0, 0);
                q = __builtin_amdgcn_mfma_f32_16x16x32_bf16(ah[mtl][1], b1l, q, 0, 0, 0);
                p = __builtin_amdgcn_mfma_f32_16x16x32_bf16(al[mtl][0], b0h, p, 0, 0, 0);
                q = __builtin_amdgcn_mfma_f32_16x16x32_bf16(al[mtl][1], b1h, q, 0, 0, 0);
                #pragma unroll
                for (int j = 0; j < 4; ++j) {
                    float s = fmaf(-2.0f, p[j] + q[j], ccv);
                    bool lt = s < best[mtl][j];
                    second[mtl][j] = fminf(second[mtl][j], fmaxf(best[mtl][j], s));
                    best[mtl][j]   = fminf(best[mtl][j], s);
                    bidx[mtl][j]   = lt ? code : bidx[mtl][j];
                }
            }
        }
    }

    #pragma unroll
    for (int m = 0; m < 2; ++m)
        #pragma unroll
        for (int j = 0; j < 4; ++j) {
            float bv = best[m][j], sv = second[m][j]; int bi = bidx[m][j];
            #pragma unroll
            for (int d = 1; d < 16; d <<= 1) {
                float ob = __shfl_xor(bv, d, 64);
                float os = __shfl_xor(sv, d, 64);
                int   oi = __shfl_xor(bi, d, 64);
                float loser = fmaxf(bv, ob);
                sv = fminf(fminf(sv, os), loser);
                bool sw = ob < bv;
                bv = fminf(bv, ob);
                bi = sw ? oi : bi;
            }
            if ((lane & 15) == 0) {
                int t = t0 + (wv*2 + m)*16 + (lane >> 4)*4 + j;
                if (t < T) {
                    out[((size_t)cb*64 + b)*T + t] = bi;
                    if (sv - bv < VQ_MARGIN) {
                        int pos = atomicAdd(&cnt[cb], 1);
                        list[pos] = (b << 11) | t;
                    }
                }
            }
        }
}

// ---------------- VQ rescore v3: paired same-cb flags, shared loads ---------
__global__ __launch_bounds__(256) void vq_rescore_kernel(
    const float* __restrict__ h3, const float* __restrict__ wq,
    const float* __restrict__ bq, const float* __restrict__ cbs,
    const float* __restrict__ ccg, const int* __restrict__ cnt,
    const int* __restrict__ list0, const int* __restrict__ list1,
    int* __restrict__ out)
{
    const int T = 2000;
    __shared__ float hp[4][2][448];
    __shared__ float zsh[4][2][64];
    int tid = threadIdx.x, lane = tid & 63, wv = tid >> 6;
    int cb = blockIdx.y;
    const int* list = cb ? list1 : list0;
    int count = cnt[cb];
    int gw = blockIdx.x * 4 + wv, nw = gridDim.x * 4;

    const float* cbase = cbs + (size_t)cb * 1024 * 64;
    const float* ccb   = ccg + cb * 1024;
    int d = cb * 64 + lane;
    const float4* wp = (const float4*)(wq + (size_t)d * 448);
    float bqd = bq[d];

    for (int i0 = gw * 2; i0 < count; i0 += nw * 2) {
        int e0 = list[i0];
        int e1 = (i0 + 1 < count) ? list[i0 + 1] : e0;
        int b0 = e0 >> 11, t0 = e0 & 2047;
        int b1 = e1 >> 11, t1 = e1 & 2047;

        const float* hrow0 = h3 + ((size_t)b0 * 64 + lane) * T;
        const float* hrow1 = h3 + ((size_t)b1 * 64 + lane) * T;
        #pragma unroll
        for (int kk = 0; kk < 7; ++kk) {
            int a0 = t0 - 6 + kk, a1 = t1 - 6 + kk;
            hp[wv][0][lane * 7 + kk] = (a0 >= 0) ? hrow0[a0] : 0.0f;
            hp[wv][1][lane * 7 + kk] = (a1 >= 0) ? hrow1[a1] : 0.0f;
        }

        float p00=0.f,p01=0.f,p02=0.f,p03=0.f, p10=0.f,p11=0.f,p12=0.f,p13=0.f;
        #pragma unroll 8
        for (int q = 0; q < 112; ++q) {
            float4 w4 = wp[q];
            float4 h0 = *(const float4*)&hp[wv][0][4 * q];
            float4 h1 = *(const float4*)&hp[wv][1][4 * q];
            p00 = fmaf(w4.x, h0.x, p00); p01 = fmaf(w4.y, h0.y, p01);
            p02 = fmaf(w4.z, h0.z, p02); p03 = fmaf(w4.w, h0.w, p03);
            p10 = fmaf(w4.x, h1.x, p10); p11 = fmaf(w4.y, h1.y, p11);
            p12 = fmaf(w4.z, h1.z, p12); p13 = fmaf(w4.w, h1.w, p13);
        }
        float z0 = (p00 + p01) + (p02 + p03) + bqd; z0 = z0 > 0.f ? z0 : expm1f(z0);
        float z1 = (p10 + p11) + (p12 + p13) + bqd; z1 = z1 > 0.f ? z1 : expm1f(z1);
        zsh[wv][0][lane] = z0;
        zsh[wv][1][lane] = z1;

        float bv0 = 3.4e38f, bv1 = 3.4e38f; int bi0 = 0, bi1 = 0;
        for (int ii = 0; ii < 16; ++ii) {
            int code = ii * 64 + lane;
            const float4* cp = (const float4*)(cbase + (size_t)code * 64);
            float d00=0.f,d01=0.f,d02=0.f,d03=0.f, d10=0.f,d11=0.f,d12=0.f,d13=0.f;
            #pragma unroll
            for (int q = 0; q < 16; ++q) {
                float4 cv = cp[q];
                float4 za = *(const float4*)&zsh[wv][0][4 * q];
                float4 zc = *(const float4*)&zsh[wv][1][4 * q];
                d00 = fmaf(za.x, cv.x, d00); d01 = fmaf(za.y, cv.y, d01);
                d02 = fmaf(za.z, cv.z, d02); d03 = fmaf(za.w, cv.w, d03);
                d10 = fmaf(zc.x, cv.x, d10); d11 = fmaf(zc.y, cv.y, d11);
                d12 = fmaf(zc.z, cv.z, d12); d13 = fmaf(zc.w, cv.w, d13);
            }
            float cc0 = ccb[code];
            float s0 = fmaf(-2.0f, (d00 + d01) + (d02 + d03), cc0);
            float s1 = fmaf(-2.0f, (d10 + d11) + (d12 + d13), cc0);
            if (s0 < bv0) { bv0 = s0; bi0 = code; }
            if (s1 < bv1) { bv1 = s1; bi1 = code; }
        }
        #pragma unroll
        for (int dd = 1; dd < 64; dd <<= 1) {
            float ov0 = __shfl_xor(bv0, dd, 64); int oi0 = __shfl_xor(bi0, dd, 64);
            if (ov0 < bv0 || (ov0 == bv0 && oi0 < bi0)) { bv0 = ov0; bi0 = oi0; }
            float ov1 = __shfl_xor(bv1, dd, 64); int oi1 = __shfl_xor(bi1, dd, 64);
            if (ov1 < bv1 || (ov1 == bv1 && oi1 < bi1)) { bv1 = ov1; bi1 = oi1; }
        }
        if (lane == 0) {
            out[((size_t)cb * 64 + b0) * T + t0] = bi0;
            out[((size_t)cb * 64 + b1) * T + t1] = bi1;
        }
    }
}

extern "C" void kernel_launch(void* const* d_in, const int* in_sizes, int n_in,
                              void* d_out, int out_size, void* d_ws, size_t ws_size,
                              hipStream_t stream)
{
    const float* x   = (const float*)d_in[0];
    const float* w0  = (const float*)d_in[1];
    const float* b0  = (const float*)d_in[2];
    const float* w1  = (const float*)d_in[3];
    const float* b1  = (const float*)d_in[4];
    const float* w2  = (const float*)d_in[5];
    const float* b2  = (const float*)d_in[6];
    const float* w3  = (const float*)d_in[7];
    const float* b3  = (const float*)d_in[8];
    const float* wq  = (const float*)d_in[9];
    const float* bq  = (const float*)d_in[10];
    const float* cbs = (const float*)d_in[11];
    int* out = (int*)d_out;

    constexpr int B = 64;
    constexpr size_t BUF = 24576000;
    float* bufA = (float*)d_ws;
    float* bufB = bufA + BUF;
    // prep region inside bufB's dead-h1 zone (written only after conv2).
    float* prep   = bufB + 16000000;
    short* cbf    = (short*)prep;
    float* cc     = prep + 131072;
    int*   cnt    = (int*)(cc + 2048);
    int*   list0  = (int*)(prep + 200000);
    int*   list1  = (int*)(prep + 360000);
    short* wfrag4 = (short*)(prep + 550000);      // 172032 shorts
    short* wfrag3 = (short*)(prep + 650000);      // 86016 shorts
    // conv1/conv2 weight fragments: d_out as scratch (1 MB; fully rewritten by
    // vq_mfma afterwards). wfrag1 = 12288 shorts, wfrag2 = 49152 shorts.
    short* wfrag1 = (short*)d_out;
    short* wfrag2 = (short*)d_out + 16384;

    // weight prep for conv1/conv2 (reads inputs only)
    wprep_ps_kernel<16, 32><<<1, 32, 0, stream>>>(w1, wfrag1);
    wprep_ps_kernel<32, 64><<<1, 64, 0, stream>>>(w2, wfrag2);

    // conv0: (B,1,48000) -> h0ps (B, 2x16 planes, 12000)
    conv_wave_kernel<1, 2, 4, 2, true><<<dim3(188, 1, B), 256, 0, stream>>>(
        x, w0, b0, bufA, B, 48000, 24000, 16);
    // conv1: phase-split stride-1 MFMA: (B,32,12000) -> h1ps (B, 2x32, 6000)
    conv_mfma_kernel<1, 32, 32, 2, 4, 3, true><<<dim3(94, B), 256, 0, stream>>>(
        bufA, wfrag1, b1, bufB, 12000, 12000);
    // conv2: phase-split stride-1 MFMA: (B,64,6000) -> h2 (B,64,6000) normal
    conv_mfma_kernel<1, 64, 64, 2, 4, 3, false><<<dim3(47, B), 256, 0, stream>>>(
        bufB, wfrag2, b2, bufA, 6000, 6000);

    // prep (bufB prep region free after conv2)
    vq_prep_kernel<<<8, 256, 0, stream>>>(cbs, cc, cbf);
    wprep_kernel<64, 64, 7><<<1, 64, 0, stream>>>(w3, wfrag3);
    wprep_kernel<64, 128, 7><<<1, 128, 0, stream>>>(wq, wfrag4);
    zero_cnt_kernel<<<1, 64, 0, stream>>>(cnt);

    // conv3: (B,64,6000) -> (B,64,2000)  stride 3
    conv_mfma_kernel<3, 64, 64, 1, 7, 6, false><<<dim3(32, B), 256, 0, stream>>>(
        bufA, wfrag3, b3, bufB, 6000, 2000);
    // conv4: (B,64,2000) -> (B,128,2000) stride 1
    conv_mfma_kernel<1, 64, 128, 2, 7, 6, false><<<dim3(16, B), 256, 0, stream>>>(
        bufB, wfrag4, bq, bufA, 2000, 2000);

    // VQ: split-bf16 MFMA + per-cb flag lists, then paired exact rescore
    vq_mfma_kernel<<<dim3(16, 2, B), 256, 0, stream>>>(bufA, cbf, cc, out, cnt, list0, list1);
    vq_rescore_kernel<<<dim3(512, 2), 256, 0, stream>>>(bufB, wq, bq, cbs, cc, cnt, list0, list1, out);
}

// Round 14
// 720.717 us; speedup vs baseline: 1.2448x; 1.2448x over previous
//
#include <hip/hip_runtime.h>
#include <hip/hip_bf16.h>
#include <cstddef>

// ---------------------------------------------------------------------------
// EncoderModule: 5x causal conv1d (K=7) + ELU, then 2x VQ argmin (1024 codes, D=64)
// B=64, L=48000, strides 2,2,2,3,1; channels 1->16->32->64->64->128
// Output: int32 indices, shape (2, 64, 2000)
//
// Inter-layer tensors: fp32, t-major [t][ci] (coalesced for both producer
// writes and consumer staging reads). Convs 1-4: 6-term split3-bf16 MFMA
// (round-11 numerics, which passed absmax 0). Staging: float4 global reads ->
// register split3 -> conflict-free ds_write_b64 into 3 LDS planes; MFMA read
// path identical to round 11's verified XOR-swizzle.
// VQ: split-bf16 MFMA scores; gap < 0.04 -> flag; paired exact fp32 rescore.
// ---------------------------------------------------------------------------

using bf16x8 = __attribute__((ext_vector_type(8))) short;
using s16x4  = __attribute__((ext_vector_type(4))) short;
using f32x4  = __attribute__((ext_vector_type(4))) float;

static __device__ __forceinline__ short f2bf(float f) {
    __hip_bfloat16 h = __float2bfloat16(f);   // RNE
    union { __hip_bfloat16 h; short s; } u; u.h = h;
    return u.s;
}
static __device__ __forceinline__ float bf2f(short s) {
    union { unsigned u; float f; } v;
    v.u = ((unsigned)(unsigned short)s) << 16;
    return v.f;
}
static __device__ __forceinline__ void split3(float v, short& s0, short& s1, short& s2) {
    s0 = f2bf(v);  float r1 = v  - bf2f(s0);   // exact
    s1 = f2bf(r1); float r2 = r1 - bf2f(s1);   // exact
    s2 = f2bf(r2);                             // residual ~2^-24 |v|
}
static __device__ __forceinline__ float elu(float v) {
    return v > 0.0f ? v : expm1f(v);
}

// ---------------- conv0: fp32 VALU, t-major phase-split store ---------------
// x (B,1,48000) -> H0 fp32 [B][12000][32], row u: ch = co + 16*(t&1), t=2u/2u+1
__global__ __launch_bounds__(256) void conv0_kernel(
    const float* __restrict__ x, const float* __restrict__ w,
    const float* __restrict__ bias, float* __restrict__ H0)
{
    __shared__ float xs[261];                  // (128-1)*2+7
    int tb = blockIdx.x, b = blockIdx.y;
    int t0 = tb * 128;
    int tid = threadIdx.x, lane = tid & 63;
    int wv = __builtin_amdgcn_readfirstlane(tid >> 6);

    const float* xb = x + (size_t)b * 48000;
    int g0 = t0 * 2 - 6;
    for (int i = tid; i < 261; i += 256) {
        int gx = g0 + i;
        xs[i] = (gx >= 0 && gx < 48000) ? xb[gx] : 0.0f;
    }
    __syncthreads();

    int co0 = wv * 4;
    float acc[4][2];
    #pragma unroll
    for (int c = 0; c < 4; ++c) { acc[c][0] = 0.f; acc[c][1] = 0.f; }

    float xw[2][7];
    #pragma unroll
    for (int u = 0; u < 2; ++u)
        #pragma unroll
        for (int k = 0; k < 7; ++k)
            xw[u][k] = xs[(lane + 64 * u) * 2 + k];
    #pragma unroll
    for (int c = 0; c < 4; ++c) {
        const float* wp = w + (size_t)(co0 + c) * 7;   // s_load
        #pragma unroll
        for (int k = 0; k < 7; ++k) {
            float wk = wp[k];
            acc[c][0] = fmaf(wk, xw[0][k], acc[c][0]);
            acc[c][1] = fmaf(wk, xw[1][k], acc[c][1]);
        }
    }

    #pragma unroll
    for (int u = 0; u < 2; ++u) {
        int t = t0 + lane + 64 * u;
        if (t < 24000) {
            float4 vv;
            vv.x = elu(acc[0][u] + bias[co0 + 0]);
            vv.y = elu(acc[1][u] + bias[co0 + 1]);
            vv.z = elu(acc[2][u] + bias[co0 + 2]);
            vv.w = elu(acc[3][u] + bias[co0 + 3]);
            *(float4*)(H0 + ((size_t)b * 12000 + (t >> 1)) * 32 + (t & 1) * 16 + co0) = vv;
        }
    }
}

// ---------------- weight prep: 3-level bf16 A-fragments ---------------------
// A element (m = mt*16 + (lane&15), k = kc*32 + (lane>>4)*8 + j)
template<int CIN, int COUT, int TAPS>
__global__ void wprep3_kernel(const float* __restrict__ w, short* __restrict__ frag)
{
    constexpr int KC = CIN / 32;
    int co = threadIdx.x;
    if (co >= COUT) return;
    int mt = co >> 4, nc = co & 15;
    for (int kc = 0; kc < KC; ++kc)
        for (int k = 0; k < TAPS; ++k)
            #pragma unroll
            for (int lh = 0; lh < 4; ++lh) {
                bf16x8 p0, p1, p2;
                #pragma unroll
                for (int j = 0; j < 8; ++j) {
                    int ci = kc * 32 + lh * 8 + j;
                    float f = w[(size_t)co * CIN * 7 + ci * 7 + k];
                    short a, bb, c; split3(f, a, bb, c);
                    p0[j] = a; p1[j] = bb; p2[j] = c;
                }
                size_t base = ((size_t)(mt * KC + kc) * TAPS + k) * 3;
                int off = (lh * 16 + nc) * 8;
                *(bf16x8*)(frag + (base + 0) * 512 + off) = p0;
                *(bf16x8*)(frag + (base + 1) * 512 + off) = p1;
                *(bf16x8*)(frag + (base + 2) * 512 + off) = p2;
            }
}

// phase-split packing (stride-2 K=7 -> stride-1 K=4 over doubled channels)
template<int CINH, int COUT>
__global__ void wprep3_ps_kernel(const float* __restrict__ w, short* __restrict__ frag)
{
    constexpr int CIN = 2 * CINH;
    constexpr int KC  = CIN / 32;
    int co = threadIdx.x;
    if (co >= COUT) return;
    int mt = co >> 4, nc = co & 15;
    for (int kc = 0; kc < KC; ++kc)
        for (int m = 0; m < 4; ++m)
            #pragma unroll
            for (int lh = 0; lh < 4; ++lh) {
                bf16x8 p0, p1, p2;
                #pragma unroll
                for (int j = 0; j < 8; ++j) {
                    int cp = kc * 32 + lh * 8 + j;
                    float f;
                    if (cp < CINH)  f = w[(size_t)co * CINH * 7 + cp * 7 + 2 * m];
                    else if (m < 3) f = w[(size_t)co * CINH * 7 + (cp - CINH) * 7 + 2 * m + 1];
                    else            f = 0.0f;
                    short a, bb, c; split3(f, a, bb, c);
                    p0[j] = a; p1[j] = bb; p2[j] = c;
                }
                size_t base = ((size_t)(mt * KC + kc) * 4 + m) * 3;
                int off = (lh * 16 + nc) * 8;
                *(bf16x8*)(frag + (base + 0) * 512 + off) = p0;
                *(bf16x8*)(frag + (base + 1) * 512 + off) = p1;
                *(bf16x8*)(frag + (base + 2) * 512 + off) = p2;
            }
}

// ---------------- conv via 6-term split3-bf16 MFMA, t-major fp32 I/O --------
// OUTMODE: 0 = fp32 t-major [t][COUT]; 1 = phase-split [t>>1][co+COUT*(t&1)];
//          2 = fp32 [co][t] (z output)
template<int S, int CIN, int COUT, int NTL, int TAPS, int PAD, int OUTMODE>
__global__ __launch_bounds__(256) void conv_mfma3_kernel(
    const float* __restrict__ Hin, const short* __restrict__ wfrag,
    const float* __restrict__ bias, float* __restrict__ Hout,
    int Lin, int Lout)
{
    constexpr int KC   = CIN / 32;
    constexpr int MT   = COUT / 16;
    constexpr int NT   = NTL * 64;
    constexpr int ROWS = (NT - 1) * S + TAPS;
    constexpr int ROWB = CIN * 2;         // plane row bytes
    constexpr int NSL  = CIN / 4;         // float4 slots per input row
    __shared__ __align__(16) short pl0[ROWS * CIN];
    __shared__ __align__(16) short pl1[ROWS * CIN];
    __shared__ __align__(16) short pl2[ROWS * CIN];

    int nb = blockIdx.x, b = blockIdx.y;
    int t0 = nb * NT;
    int tid = threadIdx.x, lane = tid & 63, wv = tid >> 6;
    int g0 = t0 * S - PAD;

    // staging: coalesced float4 reads -> register split3 -> ds_write_b64 x3
    // (consecutive lanes = consecutive channel slots -> conflict-free)
    const float* inb = Hin + (size_t)b * Lin * CIN;
    for (int e = tid; e < ROWS * NSL; e += 256) {
        int rr = e / NSL, sl = e % NSL;
        int g = g0 + rr;
        float4 v = {0.f, 0.f, 0.f, 0.f};
        if (g >= 0 && g < Lin)
            v = *(const float4*)(inb + (size_t)g * CIN + sl * 4);
        int xr = (CIN == 64) ? (rr & 7) : ((rr >> 1) & 3);
        int byte = rr * ROWB + ((((sl >> 1) ^ xr) << 4) | ((sl & 1) << 3));
        s16x4 q0, q1, q2;
        short a0, a1, a2;
        split3(v.x, a0, a1, a2); q0[0] = a0; q1[0] = a1; q2[0] = a2;
        split3(v.y, a0, a1, a2); q0[1] = a0; q1[1] = a1; q2[1] = a2;
        split3(v.z, a0, a1, a2); q0[2] = a0; q1[2] = a1; q2[2] = a2;
        split3(v.w, a0, a1, a2); q0[3] = a0; q1[3] = a1; q2[3] = a2;
        *(s16x4*)((char*)pl0 + byte) = q0;
        *(s16x4*)((char*)pl1 + byte) = q1;
        *(s16x4*)((char*)pl2 + byte) = q2;
    }
    __syncthreads();

    f32x4 acc[NTL][MT];
    #pragma unroll
    for (int n = 0; n < NTL; ++n)
        #pragma unroll
        for (int m = 0; m < MT; ++m) acc[n][m] = (f32x4){0.f, 0.f, 0.f, 0.f};

    int ncol = lane & 15, nq = lane >> 4;

    for (int k = 0; k < TAPS; ++k) {
        #pragma unroll
        for (int kc = 0; kc < KC; ++kc) {
            int colb = (kc * 32 + nq * 8) * 2;
            bf16x8 B0[NTL], B1[NTL], B2[NTL];
            #pragma unroll
            for (int ntl = 0; ntl < NTL; ++ntl) {
                int r  = S * ((wv * NTL + ntl) * 16 + ncol) + k;
                int xr = (CIN == 64) ? (r & 7) : ((r >> 1) & 3);
                int byte = r * ROWB + (colb ^ (xr << 4));
                B0[ntl] = *(const bf16x8*)((char*)pl0 + byte);
                B1[ntl] = *(const bf16x8*)((char*)pl1 + byte);
                B2[ntl] = *(const bf16x8*)((char*)pl2 + byte);
            }
            #pragma unroll
            for (int m = 0; m < MT; ++m) {
                size_t base = ((size_t)(m * KC + kc) * TAPS + k) * 3;
                bf16x8 a0 = *(const bf16x8*)(wfrag + (base + 0) * 512 + lane * 8);
                bf16x8 a1 = *(const bf16x8*)(wfrag + (base + 1) * 512 + lane * 8);
                bf16x8 a2 = *(const bf16x8*)(wfrag + (base + 2) * 512 + lane * 8);
                #pragma unroll
                for (int ntl = 0; ntl < NTL; ++ntl) {
                    f32x4 a = acc[ntl][m];
                    a = __builtin_amdgcn_mfma_f32_16x16x32_bf16(a0, B0[ntl], a, 0, 0, 0);
                    a = __builtin_amdgcn_mfma_f32_16x16x32_bf16(a1, B0[ntl], a, 0, 0, 0);
                    a = __builtin_amdgcn_mfma_f32_16x16x32_bf16(a2, B0[ntl], a, 0, 0, 0);
                    a = __builtin_amdgcn_mfma_f32_16x16x32_bf16(a0, B1[ntl], a, 0, 0, 0);
                    a = __builtin_amdgcn_mfma_f32_16x16x32_bf16(a1, B1[ntl], a, 0, 0, 0);
                    a = __builtin_amdgcn_mfma_f32_16x16x32_bf16(a0, B2[ntl], a, 0, 0, 0);
                    acc[ntl][m] = a;
                }
            }
        }
    }

    // epilogue: bias+ELU, float4 stores straight from accumulators
    #pragma unroll
    for (int ntl = 0; ntl < NTL; ++ntl) {
        int n = t0 + (wv * NTL + ntl) * 16 + ncol;
        if (n < Lout) {
            #pragma unroll
            for (int m = 0; m < MT; ++m) {
                int co0 = m * 16 + nq * 4;
                float4 bb = *(const float4*)(bias + co0);
                float4 vv;
                vv.x = elu(acc[ntl][m][0] + bb.x);
                vv.y = elu(acc[ntl][m][1] + bb.y);
                vv.z = elu(acc[ntl][m][2] + bb.z);
                vv.w = elu(acc[ntl][m][3] + bb.w);
                if constexpr (OUTMODE == 0) {
                    *(float4*)(Hout + ((size_t)b * Lout + n) * COUT + co0) = vv;
                } else if constexpr (OUTMODE == 1) {
                    *(float4*)(Hout + ((size_t)b * (Lout >> 1) + (n >> 1)) * (2 * COUT)
                               + (n & 1) * COUT + co0) = vv;
                } else {
                    Hout[((size_t)b * COUT + co0 + 0) * Lout + n] = vv.x;
                    Hout[((size_t)b * COUT + co0 + 1) * Lout + n] = vv.y;
                    Hout[((size_t)b * COUT + co0 + 2) * Lout + n] = vv.z;
                    Hout[((size_t)b * COUT + co0 + 3) * Lout + n] = vv.w;
                }
            }
        }
    }
}

// ---------------- VQ prep: cc (fp32) + codebook hi/lo bf16 B-fragments ------
__global__ __launch_bounds__(256) void vq_prep_kernel(
    const float* __restrict__ cbs, float* __restrict__ cc, short* __restrict__ cbf)
{
    int c = blockIdx.x * 256 + threadIdx.x;   // 0..2047
    if (c >= 2048) return;
    int cb = c >> 10, nl = c & 1023;
    const float* row = cbs + (size_t)c * 64;
    float v[64];
    float s = 0.f;
    #pragma unroll
    for (int i = 0; i < 16; ++i) {
        float4 q = ((const float4*)row)[i];
        v[4*i+0] = q.x; v[4*i+1] = q.y; v[4*i+2] = q.z; v[4*i+3] = q.w;
        s += q.x*q.x + q.y*q.y + q.z*q.z + q.w*q.w;
    }
    cc[c] = s;
    int nt = nl >> 4, nc = nl & 15;
    #pragma unroll
    for (int kc = 0; kc < 2; ++kc)
        #pragma unroll
        for (int lh = 0; lh < 4; ++lh) {
            bf16x8 ph, pl;
            #pragma unroll
            for (int j = 0; j < 8; ++j) {
                float f = v[kc*32 + lh*8 + j];
                short h = f2bf(f);
                ph[j] = h;
                pl[j] = f2bf(f - bf2f(h));
            }
            size_t base = ((((size_t)cb*64 + nt)*2 + kc)*2);
            *(bf16x8*)(cbf + ((base + 0)*64 + (lh*16 + nc)) * 8) = ph;
            *(bf16x8*)(cbf + ((base + 1)*64 + (lh*16 + nc)) * 8) = pl;
        }
}

__global__ void zero_cnt_kernel(int* cnt) {
    if (threadIdx.x == 0 && blockIdx.x == 0) { cnt[0] = 0; cnt[1] = 0; }
}

// ---------------- VQ main: split-bf16 MFMA + best/second + flag -------------
#define VQ_MARGIN 0.04f

__global__ __launch_bounds__(256) void vq_mfma_kernel(
    const float* __restrict__ z, const short* __restrict__ cbf,
    const float* __restrict__ ccg, int* __restrict__ out,
    int* __restrict__ cnt, int* __restrict__ list0, int* __restrict__ list1)
{
    __shared__ short zf[2][8*2*64*8];
    __shared__ short cbc[8*2*2*64*8];
    __shared__ float ccl[128];

    const int T = 2000;
    int mblk = blockIdx.x;
    int cb   = blockIdx.y;
    int b    = blockIdx.z;
    int t0   = mblk * 128;
    int tid  = threadIdx.x;
    int lane = tid & 63;
    int wv   = tid >> 6;
    int* list = cb ? list1 : list0;

    const float* zb = z + ((size_t)b*128 + (size_t)cb*64) * T;
    bool tail = (t0 + 128 > T);
    #pragma unroll
    for (int p = 0; p < 8; ++p) {
        int d    = p*8 + (tid >> 5);
        int toff = (tid & 31) * 4;
        float qa[4];
        if (!tail) {
            float4 q = *(const float4*)(zb + (size_t)d*T + t0 + toff);
            qa[0]=q.x; qa[1]=q.y; qa[2]=q.z; qa[3]=q.w;
        } else {
            #pragma unroll
            for (int u = 0; u < 4; ++u) {
                int tt = t0 + toff + u; if (tt > T-1) tt = T-1;
                qa[u] = zb[(size_t)d*T + tt];
            }
        }
        #pragma unroll
        for (int u = 0; u < 4; ++u) {
            int tl = toff + u;
            int mt = tl >> 4;
            int lw = ((d & 31) >> 3) * 16 + (tl & 15);
            int kc = d >> 5;
            int idx = (((mt*2 + kc)*64) + lw)*8 + (d & 7);
            short h = f2bf(qa[u]);
            zf[0][idx] = h;
            zf[1][idx] = f2bf(qa[u] - bf2f(h));
        }
    }
    __syncthreads();

    bf16x8 ah[2][2], al[2][2];
    #pragma unroll
    for (int mtl = 0; mtl < 2; ++mtl)
        #pragma unroll
        for (int kc = 0; kc < 2; ++kc) {
            int idx = ((((wv*2+mtl)*2 + kc)*64) + lane)*8;
            ah[mtl][kc] = *(const bf16x8*)&zf[0][idx];
            al[mtl][kc] = *(const bf16x8*)&zf[1][idx];
        }

    float best[2][4], second[2][4]; int bidx[2][4];
    #pragma unroll
    for (int m = 0; m < 2; ++m)
        #pragma unroll
        for (int j = 0; j < 4; ++j) { best[m][j] = 3.4e38f; second[m][j] = 3.4e38f; bidx[m][j] = 0; }

    const short* cbase = cbf + (size_t)cb * (64*2*2*64*8);
    const float* ccb   = ccg + cb * 1024;

    for (int ch = 0; ch < 8; ++ch) {
        __syncthreads();
        {
            const float4* src = (const float4*)(cbase + (size_t)ch * (8*2*2*64*8));
            float4* dst = (float4*)cbc;
            #pragma unroll
            for (int i = 0; i < 8; ++i) dst[tid + 256*i] = src[tid + 256*i];
            if (tid < 128) ccl[tid] = ccb[ch*128 + tid];
        }
        __syncthreads();

        for (int ntl = 0; ntl < 8; ++ntl) {
            bf16x8 b0h = *(const bf16x8*)&cbc[(((ntl*2 + 0)*2 + 0)*64 + lane)*8];
            bf16x8 b0l = *(const bf16x8*)&cbc[(((ntl*2 + 0)*2 + 1)*64 + lane)*8];
            bf16x8 b1h = *(const bf16x8*)&cbc[(((ntl*2 + 1)*2 + 0)*64 + lane)*8];
            bf16x8 b1l = *(const bf16x8*)&cbc[(((ntl*2 + 1)*2 + 1)*64 + lane)*8];
            float ccv = ccl[ntl*16 + (lane & 15)];
            int  code = ch*128 + ntl*16 + (lane & 15);
            #pragma unroll
            for (int mtl = 0; mtl < 2; ++mtl) {
                f32x4 p = {0.f,0.f,0.f,0.f}, q = {0.f,0.f,0.f,0.f};
                p = __builtin_amdgcn_mfma_f32_16x16x32_bf16(ah[mtl][0], b0h, p, 0, 0, 0);
                q = __builtin_amdgcn_mfma_f32_16x16x32_bf16(ah[mtl][1], b1h, q, 0, 0, 0);
                p = __builtin_amdgcn_mfma_f32_16x16x32_bf16(ah[mtl][0], b0l, p, 0, 0, 0);
                q = __builtin_amdgcn_mfma_f32_16x16x32_bf16(ah[mtl][1], b1l, q, 0, 0, 0);
                p = __builtin_amdgcn_mfma_f32_16x16x32_bf16(al[mtl][0], b0h, p, 0, 0, 0);
                q = __builtin_amdgcn_mfma_f32_16x16x32_bf16(al[mtl][1], b1h, q, 0, 0, 0);
                #pragma unroll
                for (int j = 0; j < 4; ++j) {
                    float s = fmaf(-2.0f, p[j] + q[j], ccv);
                    bool lt = s < best[mtl][j];
                    second[mtl][j] = fminf(second[mtl][j], fmaxf(best[mtl][j], s));
                    best[mtl][j]   = fminf(best[mtl][j], s);
                    bidx[mtl][j]   = lt ? code : bidx[mtl][j];
                }
            }
        }
    }

    #pragma unroll
    for (int m = 0; m < 2; ++m)
        #pragma unroll
        for (int j = 0; j < 4; ++j) {
            float bv = best[m][j], sv = second[m][j]; int bi = bidx[m][j];
            #pragma unroll
            for (int d = 1; d < 16; d <<= 1) {
                float ob = __shfl_xor(bv, d, 64);
                float os = __shfl_xor(sv, d, 64);
                int   oi = __shfl_xor(bi, d, 64);
                float loser = fmaxf(bv, ob);
                sv = fminf(fminf(sv, os), loser);
                bool sw = ob < bv;
                bv = fminf(bv, ob);
                bi = sw ? oi : bi;
            }
            if ((lane & 15) == 0) {
                int t = t0 + (wv*2 + m)*16 + (lane >> 4)*4 + j;
                if (t < T) {
                    out[((size_t)cb*64 + b)*T + t] = bi;
                    if (sv - bv < VQ_MARGIN) {
                        int pos = atomicAdd(&cnt[cb], 1);
                        list[pos] = (b << 11) | t;
                    }
                }
            }
        }
}

// ---------------- VQ rescore: paired same-cb flags, t-major H3 --------------
__global__ __launch_bounds__(256) void vq_rescore_kernel(
    const float* __restrict__ H3, const float* __restrict__ wq,
    const float* __restrict__ bq, const float* __restrict__ cbs,
    const float* __restrict__ ccg, const int* __restrict__ cnt,
    const int* __restrict__ list0, const int* __restrict__ list1,
    int* __restrict__ out)
{
    const int T = 2000;
    __shared__ float hp[4][2][448];
    __shared__ float zsh[4][2][64];
    int tid = threadIdx.x, lane = tid & 63, wv = tid >> 6;
    int cb = blockIdx.y;
    const int* list = cb ? list1 : list0;
    int count = cnt[cb];
    int gw = blockIdx.x * 4 + wv, nw = gridDim.x * 4;

    const float* cbase = cbs + (size_t)cb * 1024 * 64;
    const float* ccb   = ccg + cb * 1024;
    int d = cb * 64 + lane;
    const float4* wp = (const float4*)(wq + (size_t)d * 448);
    float bqd = bq[d];

    for (int i0 = gw * 2; i0 < count; i0 += nw * 2) {
        int e0 = list[i0];
        int e1 = (i0 + 1 < count) ? list[i0 + 1] : e0;
        int b0 = e0 >> 11, t0 = e0 & 2047;
        int b1 = e1 >> 11, t1 = e1 & 2047;

        // stage 64x7 h3 patches from t-major H3 (lane = ci; coalesced rows)
        size_t base0 = (size_t)b0 * T * 64;
        size_t base1 = (size_t)b1 * T * 64;
        #pragma unroll
        for (int kk = 0; kk < 7; ++kk) {
            int a0 = t0 - 6 + kk, a1 = t1 - 6 + kk;
            hp[wv][0][lane * 7 + kk] = (a0 >= 0) ? H3[base0 + (size_t)a0 * 64 + lane] : 0.0f;
            hp[wv][1][lane * 7 + kk] = (a1 >= 0) ? H3[base1 + (size_t)a1 * 64 + lane] : 0.0f;
        }

        // exact fp32 conv4 for dim d (w stream shared across both flags)
        float p00=0.f,p01=0.f,p02=0.f,p03=0.f, p10=0.f,p11=0.f,p12=0.f,p13=0.f;
        #pragma unroll 8
        for (int q = 0; q < 112; ++q) {
            float4 w4 = wp[q];
            float4 h0 = *(const float4*)&hp[wv][0][4 * q];
            float4 h1 = *(const float4*)&hp[wv][1][4 * q];
            p00 = fmaf(w4.x, h0.x, p00); p01 = fmaf(w4.y, h0.y, p01);
            p02 = fmaf(w4.z, h0.z, p02); p03 = fmaf(w4.w, h0.w, p03);
            p10 = fmaf(w4.x, h1.x, p10); p11 = fmaf(w4.y, h1.y, p11);
            p12 = fmaf(w4.z, h1.z, p12); p13 = fmaf(w4.w, h1.w, p13);
        }
        float z0 = (p00 + p01) + (p02 + p03) + bqd; z0 = z0 > 0.f ? z0 : expm1f(z0);
        float z1 = (p10 + p11) + (p12 + p13) + bqd; z1 = z1 > 0.f ? z1 : expm1f(z1);
        zsh[wv][0][lane] = z0;
        zsh[wv][1][lane] = z1;

        // full exact scan; codebook row loads shared across both flags
        float bv0 = 3.4e38f, bv1 = 3.4e38f; int bi0 = 0, bi1 = 0;
        for (int ii = 0; ii < 16; ++ii) {
            int code = ii * 64 + lane;
            const float4* cp = (const float4*)(cbase + (size_t)code * 64);
            float d00=0.f,d01=0.f,d02=0.f,d03=0.f, d10=0.f,d11=0.f,d12=0.f,d13=0.f;
            #pragma unroll
            for (int q = 0; q < 16; ++q) {
                float4 cv = cp[q];
                float4 za = *(const float4*)&zsh[wv][0][4 * q];
                float4 zc = *(const float4*)&zsh[wv][1][4 * q];
                d00 = fmaf(za.x, cv.x, d00); d01 = fmaf(za.y, cv.y, d01);
                d02 = fmaf(za.z, cv.z, d02); d03 = fmaf(za.w, cv.w, d03);
                d10 = fmaf(zc.x, cv.x, d10); d11 = fmaf(zc.y, cv.y, d11);
                d12 = fmaf(zc.z, cv.z, d12); d13 = fmaf(zc.w, cv.w, d13);
            }
            float cc0 = ccb[code];
            float s0 = fmaf(-2.0f, (d00 + d01) + (d02 + d03), cc0);
            float s1 = fmaf(-2.0f, (d10 + d11) + (d12 + d13), cc0);
            if (s0 < bv0) { bv0 = s0; bi0 = code; }
            if (s1 < bv1) { bv1 = s1; bi1 = code; }
        }
        #pragma unroll
        for (int dd = 1; dd < 64; dd <<= 1) {
            float ov0 = __shfl_xor(bv0, dd, 64); int oi0 = __shfl_xor(bi0, dd, 64);
            if (ov0 < bv0 || (ov0 == bv0 && oi0 < bi0)) { bv0 = ov0; bi0 = oi0; }
            float ov1 = __shfl_xor(bv1, dd, 64); int oi1 = __shfl_xor(bi1, dd, 64);
            if (ov1 < bv1 || (ov1 == bv1 && oi1 < bi1)) { bv1 = ov1; bi1 = oi1; }
        }
        if (lane == 0) {
            out[((size_t)cb * 64 + b0) * T + t0] = bi0;
            out[((size_t)cb * 64 + b1) * T + t1] = bi1;
        }
    }
}

extern "C" void kernel_launch(void* const* d_in, const int* in_sizes, int n_in,
                              void* d_out, int out_size, void* d_ws, size_t ws_size,
                              hipStream_t stream)
{
    const float* x   = (const float*)d_in[0];
    const float* w0  = (const float*)d_in[1];
    const float* b0  = (const float*)d_in[2];
    const float* w1  = (const float*)d_in[3];
    const float* b1  = (const float*)d_in[4];
    const float* w2  = (const float*)d_in[5];
    const float* b2  = (const float*)d_in[6];
    const float* w3  = (const float*)d_in[7];
    const float* b3  = (const float*)d_in[8];
    const float* wq  = (const float*)d_in[9];
    const float* bq  = (const float*)d_in[10];
    const float* cbs = (const float*)d_in[11];
    int* out = (int*)d_out;

    // two 98,304,000-byte regions (proven footprint)
    char* r1 = (char*)d_ws;
    char* r2 = r1 + 98304000;
    float* H0 = (float*)r1;               // [64][12000][32] fp32 t-major (phase-split)
    float* H1 = (float*)r2;               // [64][6000][64]  (phase-split)
    float* H2 = (float*)r1;               // [64][6000][64]  (over dead H0)
    float* H3 = (float*)r2;               // [64][2000][64]  (over dead H1)
    float* z  = (float*)(r2 + 32768000);  // [64][128][2000] fp32

    // weight fragments in d_out (dead until vq_mfma rewrites it): 639 KB < 1 MB
    short* wf1 = (short*)d_out;           // 12288 shorts
    short* wf2 = wf1 + 12288;             // 49152
    short* wf3 = wf1 + 61440;             // 86016
    short* wf4 = wf1 + 147456;            // 172032 -> ends at 319488 shorts

    // VQ prep data in r1 (free after conv3 consumes H2)
    short* cbf   = (short*)r1;
    float* cc    = (float*)(r1 + 524288);
    int*   cnt   = (int*)(r1 + 540000);
    int*   list0 = (int*)(r1 + 1000000);
    int*   list1 = (int*)(r1 + 2100000);

    // weight prep (reads inputs only)
    wprep3_ps_kernel<16, 32><<<1, 32, 0, stream>>>(w1, wf1);
    wprep3_ps_kernel<32, 64><<<1, 64, 0, stream>>>(w2, wf2);
    wprep3_kernel<64, 64, 7><<<1, 64, 0, stream>>>(w3, wf3);
    wprep3_kernel<64, 128, 7><<<1, 128, 0, stream>>>(wq, wf4);

    // conv0: x -> H0 (fp32 t-major, phase-split)
    conv0_kernel<<<dim3(188, 64), 256, 0, stream>>>(x, w0, b0, H0);
    // conv1: H0 -> H1, stride-1 K=4 over 32ch, phase-split out
    conv_mfma3_kernel<1, 32, 32, 2, 4, 3, 1><<<dim3(94, 64), 256, 0, stream>>>(
        H0, wf1, b1, H1, 12000, 12000);
    // conv2: H1 -> H2, stride-1 K=4 over 64ch, t-major out
    conv_mfma3_kernel<1, 64, 64, 2, 4, 3, 0><<<dim3(47, 64), 256, 0, stream>>>(
        H1, wf2, b2, H2, 6000, 6000);
    // conv3: H2 -> H3, stride 3, K=7, t-major out
    conv_mfma3_kernel<3, 64, 64, 1, 7, 6, 0><<<dim3(32, 64), 256, 0, stream>>>(
        H2, wf3, b3, H3, 6000, 2000);

    // VQ prep into r1 (H2 now dead)
    vq_prep_kernel<<<8, 256, 0, stream>>>(cbs, cc, cbf);
    zero_cnt_kernel<<<1, 64, 0, stream>>>(cnt);

    // conv4: H3 -> z (fp32 [co][t]), stride 1, K=7
    conv_mfma3_kernel<1, 64, 128, 2, 7, 6, 2><<<dim3(16, 64), 256, 0, stream>>>(
        H3, wf4, bq, z, 2000, 2000);

    // VQ: split-bf16 MFMA + per-cb flag lists, then paired exact rescore
    vq_mfma_kernel<<<dim3(16, 2, 64), 256, 0, stream>>>(z, cbf, cc, out, cnt, list0, list1);
    vq_rescore_kernel<<<dim3(512, 2), 256, 0, stream>>>(H3, wq, bq, cbs, cc, cnt, list0, list1, out);
}